// Round 1
// baseline (24.003 us; speedup 1.0000x reference)
//
#include <hip/hip_runtime.h>

// x: (N=64, C=3, W=16, T=128, V=25, M=2) fp32, row-major
// strides (elems): N:307200, C:102400, W:6400, T:50, V:2, M:1
// b = ((n*T + t)*V + v)*M + m ; local = t*50 + v*2 + m == b % 6400 (bijective)
// xr[b][c][w] = x[n, i%3, i/3, t, v, m] with i = c*16 + w
// out: (B, 4, 4) fp32, B = 409600

__global__ void __launch_bounds__(256)
gaussian_embed_kernel(const float* __restrict__ x, float* __restrict__ out, int B) {
    int b = blockIdx.x * blockDim.x + threadIdx.x;
    if (b >= B) return;

    const int n   = b / 6400;          // 6400 = T*V*M
    const int rem = b - n * 6400;      // == t*50 + v*2 + m
    const float* __restrict__ xb = x + (size_t)n * 307200 + rem;

    // Load the 48 elements; f[i] is xr[i/16][i%16]
    float f[48];
#pragma unroll
    for (int i = 0; i < 48; ++i) {
        const int c_orig = i % 3;
        const int w_orig = i / 3;
        f[i] = xb[c_orig * 102400 + w_orig * 6400];
    }

    // Row means over W=16
    float m0 = 0.f, m1 = 0.f, m2 = 0.f;
#pragma unroll
    for (int w = 0; w < 16; ++w) { m0 += f[w]; m1 += f[16 + w]; m2 += f[32 + w]; }
    m0 *= (1.f / 16.f); m1 *= (1.f / 16.f); m2 *= (1.f / 16.f);

    // Center in place
#pragma unroll
    for (int w = 0; w < 16; ++w) { f[w] -= m0; f[16 + w] -= m1; f[32 + w] -= m2; }

    // Covariance (symmetric, /15)
    float c00 = 0.f, c01 = 0.f, c02 = 0.f, c11 = 0.f, c12 = 0.f, c22 = 0.f;
#pragma unroll
    for (int w = 0; w < 16; ++w) {
        const float a = f[w], bb = f[16 + w], cc = f[32 + w];
        c00 += a * a;  c01 += a * bb; c02 += a * cc;
        c11 += bb * bb; c12 += bb * cc; c22 += cc * cc;
    }
    const float inv15 = 1.f / 15.f;
    c00 *= inv15; c01 *= inv15; c02 *= inv15;
    c11 *= inv15; c12 *= inv15; c22 *= inv15;

    // Trace-normalize + tr*0.001 on diagonal
    const float tr    = c00 + c11 + c22;
    const float invtr = 1.f / tr;
    const float diag  = 0.001f * tr;
    const float a = c00 * invtr + diag;
    const float bq = c01 * invtr;
    const float cq = c02 * invtr;
    const float d = c11 * invtr + diag;
    const float e = c12 * invtr;
    const float g = c22 * invtr + diag;

    // 3x3 determinant (cofactor expansion)
    const float det = a * (d * g - e * e) - bq * (bq * g - cq * e) + cq * (bq * e - cq * d);
    const float dsp = powf(det, -0.25f);

    // Block [[Sigma + mu mu^T, mu],[mu^T, 1]] * dsp, row-major 4x4
    const float om01 = dsp * (bq + m0 * m1);
    const float om02 = dsp * (cq + m0 * m2);
    const float om12 = dsp * (e + m1 * m2);
    const float dm0 = dsp * m0, dm1 = dsp * m1, dm2 = dsp * m2;

    float4 r0 = make_float4(dsp * (a + m0 * m0), om01, om02, dm0);
    float4 r1 = make_float4(om01, dsp * (d + m1 * m1), om12, dm1);
    float4 r2 = make_float4(om02, om12, dsp * (g + m2 * m2), dm2);
    float4 r3 = make_float4(dm0, dm1, dm2, dsp);

    float4* __restrict__ o = (float4*)(out + (size_t)b * 16);
    o[0] = r0; o[1] = r1; o[2] = r2; o[3] = r3;
}

extern "C" void kernel_launch(void* const* d_in, const int* in_sizes, int n_in,
                              void* d_out, int out_size, void* d_ws, size_t ws_size,
                              hipStream_t stream) {
    const float* x = (const float*)d_in[0];
    float* out = (float*)d_out;
    const int B = in_sizes[0] / 48;  // 409600
    const int threads = 256;
    const int blocks = (B + threads - 1) / threads;
    gaussian_embed_kernel<<<blocks, threads, 0, stream>>>(x, out, B);
}